// Round 2
// baseline (1603.926 us; speedup 1.0000x reference)
//
#include <hip/hip_runtime.h>
#include <stdint.h>

#define NG   64
#define NTOK 8192
#define KDIM 2560
#define NDIM 1664
#define BM   128
#define BN   128
#define BK   32
#define NKITER (KDIM / BK)   /* 80 */
#define ASTR 40              /* A LDS row stride (shorts): 32 + 8 pad -> conflict-free b128 r/w */

typedef __attribute__((ext_vector_type(8))) short bf16x8;
typedef __attribute__((ext_vector_type(4))) float f32x4;
typedef __attribute__((ext_vector_type(2))) float f32x2;
typedef __attribute__((ext_vector_type(4))) unsigned int u32x4;

// pack two fp32 -> two bf16 (round-half-up) in one v_perm_b32
static __device__ __forceinline__ unsigned pk2(float a, float b) {
    unsigned ua = __float_as_uint(a) + 0x8000u;
    unsigned ub = __float_as_uint(b) + 0x8000u;
    return __builtin_amdgcn_perm(ub, ua, 0x07060302u);
}

__global__ __launch_bounds__(256, 3)
void grouped_gemm(const float* __restrict__ X, const float* __restrict__ W,
                  const int* __restrict__ counts, float* __restrict__ Y) {
    const int nt = blockIdx.x;   // 0..12  N-tile
    const int mt = blockIdx.y;   // 0..1   M-tile (CAP=256 -> <=2 tiles of 128)
    const int g  = blockIdx.z;   // 0..63  expert

    const int tid  = threadIdx.x;
    const int lane = tid & 63;
    const int wid  = tid >> 6;

    // ---- wave-parallel prefix scan of counts (NG==64==wave width) ----
    int c    = counts[lane];
    int incl = c;
    #pragma unroll
    for (int off = 1; off < 64; off <<= 1) {
        int y = __shfl_up(incl, off, 64);
        if (lane >= off) incl += y;
    }
    const int cnt   = __shfl(c, g, 64);
    const int start = __shfl(incl, g, 64) - cnt;

    const int m0 = mt * BM;
    if (m0 >= cnt) return;               // block-uniform -> safe before barriers
    const int nb = nt * BN;

    const int wm = (wid >> 1) * 64;      // 2x2 wave tiling over (M,N)
    const int wn = (wid & 1) * 64;

    __shared__ unsigned short Ash[2][BM * ASTR];   // [m][k] k-fast, stride 40
    __shared__ unsigned short Bsh[2][BN * BK];     // [n][k] k-fast, 16B XOR swizzle key=(n>>1)&3

    // ---- A staging: thread covers 8 k's of rows (ar, ar+64) ----
    const int ar  = tid >> 2;            // 0..63
    const int akq = (tid & 3) * 8;       // 0,8,16,24
    int gr0 = start + m0 + ar;       if (gr0 > NTOK - 1) gr0 = NTOK - 1;  // pad rows: junk, never stored
    int gr1 = start + m0 + ar + 64;  if (gr1 > NTOK - 1) gr1 = NTOK - 1;
    const float* ap0 = X + (size_t)gr0 * KDIM + akq;
    const float* ap1 = X + (size_t)gr1 * KDIM + akq;

    // ---- B staging: wave wid owns k-group [wid*8, wid*8+8); lane covers n = nb+lane*2, +1 ----
    const float* bp = W + (size_t)g * KDIM * NDIM + (size_t)(wid * 8) * NDIM + nb + lane * 2;
    // LDS write (shorts): (n)*32 + (wid ^ (lane&3))*8   [one b128 per column jj]
    const int bw0 = (lane * 2) * BK + ((wid ^ (lane & 3)) * 8);

    f32x4 acc[4][4];
    #pragma unroll
    for (int i = 0; i < 4; ++i)
        #pragma unroll
        for (int j = 0; j < 4; ++j)
            acc[i][j] = (f32x4)0.0f;

    const int fm = lane & 15;
    const int fq = lane >> 4;

    // preload K-tile 0
    f32x4 a0 = *(const f32x4*)(ap0);  f32x4 a1 = *(const f32x4*)(ap0 + 4);
    f32x4 a2 = *(const f32x4*)(ap1);  f32x4 a3 = *(const f32x4*)(ap1 + 4);
    f32x2 wv[8];
    #pragma unroll
    for (int r = 0; r < 8; ++r) wv[r] = *(const f32x2*)(bp + (size_t)r * NDIM);
    ap0 += BK; ap1 += BK; bp += (size_t)BK * NDIM;

    for (int kt = 0; kt < NKITER; ++kt) {
        const int b = kt & 1;
        // ---- pack + stage tile kt into LDS[b] (consumes prefetched regs) ----
        u32x4 pa0 = { pk2(a0[0],a0[1]), pk2(a0[2],a0[3]), pk2(a1[0],a1[1]), pk2(a1[2],a1[3]) };
        u32x4 pa1 = { pk2(a2[0],a2[1]), pk2(a2[2],a2[3]), pk2(a3[0],a3[1]), pk2(a3[2],a3[3]) };
        *(u32x4*)&Ash[b][ar * ASTR + akq]        = pa0;
        *(u32x4*)&Ash[b][(ar + 64) * ASTR + akq] = pa1;
        #pragma unroll
        for (int jj = 0; jj < 2; ++jj) {
            u32x4 pb = { pk2(wv[0][jj], wv[1][jj]), pk2(wv[2][jj], wv[3][jj]),
                         pk2(wv[4][jj], wv[5][jj]), pk2(wv[6][jj], wv[7][jj]) };
            *(u32x4*)&Bsh[b][bw0 + jj * BK] = pb;
        }
        __syncthreads();   // single barrier: nothing outstanding in vmem here -> cheap drain
        // ---- prefetch K-tile kt+1 (full-iteration latency window) ----
        if (kt + 1 < NKITER) {
            a0 = *(const f32x4*)(ap0);  a1 = *(const f32x4*)(ap0 + 4);
            a2 = *(const f32x4*)(ap1);  a3 = *(const f32x4*)(ap1 + 4);
            #pragma unroll
            for (int r = 0; r < 8; ++r) wv[r] = *(const f32x2*)(bp + (size_t)r * NDIM);
            ap0 += BK; ap1 += BK; bp += (size_t)BK * NDIM;
        }
        // ---- fragments (8 x ds_read_b128, conflict-free) + 16 MFMA ----
        bf16x8 af[4], bfr[4];
        #pragma unroll
        for (int i = 0; i < 4; ++i)
            af[i] = *(const bf16x8*)&Ash[b][(wm + i * 16 + fm) * ASTR + fq * 8];
        #pragma unroll
        for (int j = 0; j < 4; ++j) {
            int n  = wn + j * 16 + fm;
            int su = fq ^ ((n >> 1) & 3);
            bfr[j] = *(const bf16x8*)&Bsh[b][n * BK + su * 8];
        }
        #pragma unroll
        for (int i = 0; i < 4; ++i)
            #pragma unroll
            for (int j = 0; j < 4; ++j)
                acc[i][j] = __builtin_amdgcn_mfma_f32_16x16x32_bf16(af[i], bfr[j], acc[i][j], 0, 0, 0);
    }

    // ---- epilogue: C/D layout col=lane&15, row=(lane>>4)*4+reg [m89] ----
    const int r4 = fq * 4;
    #pragma unroll
    for (int i = 0; i < 4; ++i) {
        int mlbase = m0 + wm + i * 16 + r4;
        #pragma unroll
        for (int j = 0; j < 4; ++j) {
            int col = nb + wn + j * 16 + fm;
            #pragma unroll
            for (int rr = 0; rr < 4; ++rr) {
                int row = mlbase + rr;
                if (row < cnt)
                    Y[(size_t)(start + row) * NDIM + col] = acc[i][j][rr];
            }
        }
    }
}

extern "C" void kernel_launch(void* const* d_in, const int* in_sizes, int n_in,
                              void* d_out, int out_size, void* d_ws, size_t ws_size,
                              hipStream_t stream) {
    const float* X      = (const float*)d_in[0];
    const float* W      = (const float*)d_in[1];
    const int*   counts = (const int*)d_in[2];
    float*       Y      = (float*)d_out;
    dim3 grid(NDIM / BN, 2, NG);   // 13 x 2 x 64
    grouped_gemm<<<grid, 256, 0, stream>>>(X, W, counts, Y);
}